// Round 9
// baseline (1009.443 us; speedup 1.0000x reference)
//
#include <hip/hip_runtime.h>
#include <hip/hip_bf16.h>

// Problem constants
#define BB 32
#define QQ 300
#define DD 256
#define HH 8
#define DHH 32
#define LL 4
#define PP 4
#define SS 8500

typedef __attribute__((ext_vector_type(8))) short bf16x8;
typedef __attribute__((ext_vector_type(4))) float f32x4;

__device__ inline unsigned short f2bf(float f) {
  unsigned int u = __builtin_bit_cast(unsigned int, f);
  unsigned int r = (u + 0x7FFFu + ((u >> 16) & 1u)) >> 16;
  return (unsigned short)r;
}

// ---------------------------------------------------------------------------
// Convert W_val (256x256 f32, [k][n]) -> bf16 [n][k] with T2 XOR swizzle
// ---------------------------------------------------------------------------
__global__ __launch_bounds__(256) void wcvt_kernel(const float* __restrict__ W,
                                                   unsigned short* __restrict__ wbfS) {
  int t = blockIdx.x * 256 + threadIdx.x;   // 0..65535
  int k = t >> 8, n = t & 255;              // coalesced read of W[k][*]
  wbfS[n * 256 + (k ^ ((n & 7) << 3))] = f2bf(W[(size_t)k * 256 + n]);
}

// ---------------------------------------------------------------------------
// Value GEMM (unchanged from R7 — ~80 us, 4 blocks/CU):
// C[M x 256] = bf16(A[M x 256] f32) @ bf16(W) + bias.
// ---------------------------------------------------------------------------
__global__ __launch_bounds__(256, 4) void gemm_val_mfma(
    const float* __restrict__ A, const unsigned short* __restrict__ WbfS,
    const float* __restrict__ bias, __hip_bfloat16* __restrict__ C) {
  __shared__ __align__(16) unsigned short Alds[64 * 64];  // 8 KB, swizzled
  __shared__ __align__(16) unsigned short Blds[256 * 64]; // 32 KB, swizzled

  const int t = threadIdx.x;
  const int lane = t & 63;
  const int w = t >> 6;
  const int lm = lane & 15, lg = lane >> 4;
  const int row0 = blockIdx.x * 64;

  f32x4 acc[16];
#pragma unroll
  for (int nf = 0; nf < 16; ++nf) acc[nf] = {0.f, 0.f, 0.f, 0.f};

  for (int k0 = 0; k0 < 256; k0 += 64) {
#pragma unroll
    for (int i = 0; i < 8; ++i) {
      const unsigned short* gp = WbfS +
          (size_t)(w * 64 + i * 8 + (lane >> 3)) * 256 + k0 + (lane & 7) * 8;
      unsigned char* lp = reinterpret_cast<unsigned char*>(Blds) + (w * 8 + i) * 1024;
      __builtin_amdgcn_global_load_lds(
          (const __attribute__((address_space(1))) void*)gp,
          (__attribute__((address_space(3))) void*)lp, 16, 0, 0);
    }
#pragma unroll
    for (int i = 0; i < 4; ++i) {
      int u = i * 256 + t;
      int r = u >> 4, c4 = (u & 15) * 4;
      float4 v = *reinterpret_cast<const float4*>(A + (size_t)(row0 + r) * 256 + k0 + c4);
      ushort4 h;
      h.x = f2bf(v.x); h.y = f2bf(v.y); h.z = f2bf(v.z); h.w = f2bf(v.w);
      *reinterpret_cast<ushort4*>(&Alds[r * 64 + (c4 ^ ((r & 7) << 3))]) = h;
    }
    __syncthreads();

#pragma unroll
    for (int ks = 0; ks < 2; ++ks) {
      const int kk = (ks * 32 + lg * 8) ^ ((lm & 7) << 3);
      const bf16x8 af = *reinterpret_cast<const bf16x8*>(&Alds[(w * 16 + lm) * 64 + kk]);
#pragma unroll
      for (int nf = 0; nf < 16; ++nf) {
        const bf16x8 bfr = *reinterpret_cast<const bf16x8*>(&Blds[(nf * 16 + lm) * 64 + kk]);
        acc[nf] = __builtin_amdgcn_mfma_f32_16x16x32_bf16(af, bfr, acc[nf], 0, 0, 0);
      }
    }
    __syncthreads();
  }

  const int rb = row0 + w * 16 + lg * 4;
#pragma unroll
  for (int nf = 0; nf < 16; ++nf) {
    const int col = nf * 16 + lm;
    const float bv = bias[col];
#pragma unroll
    for (int j = 0; j < 4; ++j)
      C[(size_t)(rb + j) * 256 + col] = __float2bfloat16(acc[nf][j] + bv);
  }
}

// ---------------------------------------------------------------------------
// Fused per-query pipeline, W-read-once-per-block layout.
// Block = 512 threads, 16 queries. Phase 1: thread owns ONE off-col (8 q)
// + ONE attn-col (4 q). Phase 2: 16q x 32thr sampling. Phase 3: thread owns
// one out-col for 8 q. W traffic: ~640 KB per block (once).
// ---------------------------------------------------------------------------
#define QPB 16

__global__ __launch_bounds__(512, 4) void fused_query_kernel(
    const float* __restrict__ hidden, const __hip_bfloat16* __restrict__ value,
    const float* __restrict__ refpts,
    const float* __restrict__ W_off, const float* __restrict__ b_off,
    const float* __restrict__ W_attn, const float* __restrict__ b_attn,
    const float* __restrict__ W_out, const float* __restrict__ b_out,
    float* __restrict__ out) {
  __shared__ float s_hid[QPB][256];
  __shared__ float s_off[QPB][256];
  __shared__ float s_lg[QPB][128];
  __shared__ float s_samp[QPB][256];
  __shared__ float s_ref[QPB][4];

  const int nb = gridDim.x;   // 600, divisible by 8
  const int bswz = (blockIdx.x % 8) * (nb / 8) + blockIdx.x / 8;
  const int bq0 = bswz * QPB;
  const int t = threadIdx.x;

  // Phase 0: stage hidden rows + refpts
#pragma unroll
  for (int i = 0; i < QPB * 256 / 512; ++i) {
    int idx = i * 512 + t;
    s_hid[idx >> 8][idx & 255] = hidden[(size_t)bq0 * 256 + idx];
  }
  if (t < QPB * 4) s_ref[t >> 2][t & 3] = refpts[(size_t)bq0 * 4 + t];
  __syncthreads();

  // Phase 1: off (col t&255, q-half t>>8) + attn (col t&127, q-quarter t>>7)
  {
    const int co = t & 255;
    const int ca = t & 127;
    const int qh = t >> 8;             // 0..1
    const int qa = t >> 7;             // 0..3
    const int ao = (qa & 1) * 4;       // attn q-offset inside the half
    float accO[8], accL[4];
    const float bo = b_off[co];
#pragma unroll
    for (int c = 0; c < 8; ++c) accO[c] = 0.f;
#pragma unroll
    for (int c = 0; c < 4; ++c) accL[c] = 0.f;
    for (int k0 = 0; k0 < 256; k0 += 4) {
      float4 hv[8];
#pragma unroll
      for (int qq = 0; qq < 8; ++qq)
        hv[qq] = *reinterpret_cast<const float4*>(&s_hid[qh * 8 + qq][k0]);
      float wo[4], wa[4];
#pragma unroll
      for (int u = 0; u < 4; ++u) {
        wo[u] = W_off[(size_t)(k0 + u) * 256 + co];
        wa[u] = W_attn[(size_t)(k0 + u) * 128 + ca];
      }
#pragma unroll
      for (int qq = 0; qq < 8; ++qq)
        accO[qq] += hv[qq].x * wo[0] + hv[qq].y * wo[1] + hv[qq].z * wo[2] + hv[qq].w * wo[3];
#pragma unroll
      for (int j = 0; j < 4; ++j)
        accL[j] += hv[ao + j].x * wa[0] + hv[ao + j].y * wa[1] +
                   hv[ao + j].z * wa[2] + hv[ao + j].w * wa[3];
    }
    const float ba = b_attn[ca];
#pragma unroll
    for (int qq = 0; qq < 8; ++qq) s_off[qh * 8 + qq][co] = accO[qq] + bo;
#pragma unroll
    for (int j = 0; j < 4; ++j) s_lg[qa * 4 + j][ca] = accL[j] + ba;
  }
  __syncthreads();

  // Phase 2: softmax (per-head, redundant x4) + bilinear sampling
  {
    const int q = t >> 5;       // 0..15
    const int sub = t & 31;
    const int h = sub >> 2;
    const int c4 = sub & 3;
    const int bq = bq0 + q;
    const int b = bq / QQ;

    float w[16];
    {
      const float* lg = &s_lg[q][h * 16];
      float m = lg[0];
#pragma unroll
      for (int j = 1; j < 16; ++j) m = fmaxf(m, lg[j]);
      float s = 0.f;
#pragma unroll
      for (int j = 0; j < 16; ++j) { w[j] = __expf(lg[j] - m); s += w[j]; }
      float inv = 1.f / s;
#pragma unroll
      for (int j = 0; j < 16; ++j) w[j] *= inv;
    }

    const float rx = s_ref[q][0], ry = s_ref[q][1];
    const float rw = s_ref[q][2], rh = s_ref[q][3];
    const unsigned short* vb =
        (const unsigned short*)value + (size_t)b * SS * DD + h * DHH + c4 * 8;

    float acc[8];
#pragma unroll
    for (int j = 0; j < 8; ++j) acc[j] = 0.f;

    const int dims[4] = {80, 40, 20, 10};
    const int sts[4] = {0, 6400, 8000, 8400};

#pragma unroll
    for (int l = 0; l < LL; ++l) {
      const int dim = dims[l];
      const int st = sts[l];
      const float fdim = (float)dim;
#pragma unroll
      for (int p = 0; p < PP; ++p) {
        const int tapi = l * 4 + p;
        const int oi = (h * 16 + tapi) * 2;
        const float locx = rx + s_off[q][oi] * rw * 0.125f;
        const float locy = ry + s_off[q][oi + 1] * rh * 0.125f;
        const float x = locx * fdim - 0.5f;
        const float y = locy * fdim - 0.5f;
        const float x0f = floorf(x), y0f = floorf(y);
        const float fx = x - x0f, fy = y - y0f;
        const int x0 = (int)x0f, y0 = (int)y0f;
        const float wt = w[tapi];
        const float bw[4] = {(1.f - fx) * (1.f - fy), fx * (1.f - fy),
                             (1.f - fx) * fy, fx * fy};
        const int cx[4] = {x0, x0 + 1, x0, x0 + 1};
        const int cy[4] = {y0, y0, y0 + 1, y0 + 1};
#pragma unroll
        for (int c = 0; c < 4; ++c) {
          const int xi = cx[c], yi = cy[c];
          const bool valid = (xi >= 0) & (xi < dim) & (yi >= 0) & (yi < dim);
          const int xc = min(max(xi, 0), dim - 1);
          const int yc = min(max(yi, 0), dim - 1);
          const uint4 v = *reinterpret_cast<const uint4*>(
              vb + (size_t)(st + yc * dim + xc) * DD);
          const float wv = valid ? bw[c] * wt : 0.f;
          const unsigned u[4] = {v.x, v.y, v.z, v.w};
#pragma unroll
          for (int k = 0; k < 4; ++k) {
            const float lo = __builtin_bit_cast(float, u[k] << 16);
            const float hi = __builtin_bit_cast(float, u[k] & 0xFFFF0000u);
            acc[2 * k] += lo * wv;
            acc[2 * k + 1] += hi * wv;
          }
        }
      }
    }
#pragma unroll
    for (int j = 0; j < 8; ++j) s_samp[q][h * DHH + c4 * 8 + j] = acc[j];
  }
  __syncthreads();

  // Phase 3: out = samp @ W_out + b_out (col t&255, q-half t>>8)
  {
    const int c = t & 255;
    const int qh = t >> 8;
    float accU[8];
#pragma unroll
    for (int qq = 0; qq < 8; ++qq) accU[qq] = 0.f;
    for (int k0 = 0; k0 < 256; k0 += 4) {
      float4 sv[8];
#pragma unroll
      for (int qq = 0; qq < 8; ++qq)
        sv[qq] = *reinterpret_cast<const float4*>(&s_samp[qh * 8 + qq][k0]);
      float wu[4];
#pragma unroll
      for (int u = 0; u < 4; ++u) wu[u] = W_out[(size_t)(k0 + u) * 256 + c];
#pragma unroll
      for (int qq = 0; qq < 8; ++qq)
        accU[qq] += sv[qq].x * wu[0] + sv[qq].y * wu[1] + sv[qq].z * wu[2] + sv[qq].w * wu[3];
    }
    const float bu = b_out[c];
#pragma unroll
    for (int qq = 0; qq < 8; ++qq)
      out[(size_t)(bq0 + qh * 8 + qq) * 256 + c] = accU[qq] + bu;
  }
}

// ---------------------------------------------------------------------------
// Launch
// ---------------------------------------------------------------------------
extern "C" void kernel_launch(void* const* d_in, const int* in_sizes, int n_in,
                              void* d_out, int out_size, void* d_ws, size_t ws_size,
                              hipStream_t stream) {
  const float* hidden = (const float*)d_in[0];
  const float* ehs    = (const float*)d_in[1];
  const float* refpts = (const float*)d_in[2];
  const float* W_val  = (const float*)d_in[3];
  const float* b_val  = (const float*)d_in[4];
  const float* W_off  = (const float*)d_in[5];
  const float* b_off  = (const float*)d_in[6];
  const float* W_attn = (const float*)d_in[7];
  const float* b_attn = (const float*)d_in[8];
  const float* W_out  = (const float*)d_in[9];
  const float* b_out  = (const float*)d_in[10];
  float* out = (float*)d_out;

  // Workspace layout
  char* ws = (char*)d_ws;
  __hip_bfloat16* value = (__hip_bfloat16*)ws;                 // 139,264,000 B
  unsigned short* wbfS = (unsigned short*)(ws + 139264000);    // 131,072 B

  const int M_val = BB * SS;   // 272000
  const int M_q   = BB * QQ;   // 9600

  // 0. W_val -> bf16 [n][k], XOR-swizzled
  wcvt_kernel<<<256, 256, 0, stream>>>(W_val, wbfS);
  // 1. value = ehs @ W_val + b_val  (bf16 MFMA)
  gemm_val_mfma<<<M_val / 64, 256, 0, stream>>>(ehs, wbfS, b_val, value);
  // 2. fused: off/attn projections + softmax + sampling + out projection
  fused_query_kernel<<<M_q / QPB, 512, 0, stream>>>(
      hidden, value, refpts, W_off, b_off, W_attn, b_attn, W_out, b_out, out);
}

// Round 11
// 274.031 us; speedup vs baseline: 3.6837x; 3.6837x over previous
//
#include <hip/hip_runtime.h>
#include <hip/hip_bf16.h>

// Problem constants
#define BB 32
#define QQ 300
#define DD 256
#define HH 8
#define DHH 32
#define LL 4
#define PP 4
#define SS 8500

typedef __attribute__((ext_vector_type(8))) short bf16x8;
typedef __attribute__((ext_vector_type(4))) float f32x4;

__device__ inline unsigned short f2bf(float f) {
  unsigned int u = __builtin_bit_cast(unsigned int, f);
  unsigned int r = (u + 0x7FFFu + ((u >> 16) & 1u)) >> 16;
  return (unsigned short)r;
}

// ---------------------------------------------------------------------------
// Convert W_val (256x256 f32, [k][n]) -> bf16 [n][k] with T2 XOR swizzle
// ---------------------------------------------------------------------------
__global__ __launch_bounds__(256) void wcvt_kernel(const float* __restrict__ W,
                                                   unsigned short* __restrict__ wbfS) {
  int t = blockIdx.x * 256 + threadIdx.x;   // 0..65535
  int k = t >> 8, n = t & 255;              // coalesced read of W[k][*]
  wbfS[n * 256 + (k ^ ((n & 7) << 3))] = f2bf(W[(size_t)k * 256 + n]);
}

// ---------------------------------------------------------------------------
// Value GEMM (unchanged — ~80 us, 4 blocks/CU):
// C[M x 256] = bf16(A[M x 256] f32) @ bf16(W) + bias.
// ---------------------------------------------------------------------------
__global__ __launch_bounds__(256, 4) void gemm_val_mfma(
    const float* __restrict__ A, const unsigned short* __restrict__ WbfS,
    const float* __restrict__ bias, __hip_bfloat16* __restrict__ C) {
  __shared__ __align__(16) unsigned short Alds[64 * 64];  // 8 KB, swizzled
  __shared__ __align__(16) unsigned short Blds[256 * 64]; // 32 KB, swizzled

  const int t = threadIdx.x;
  const int lane = t & 63;
  const int w = t >> 6;
  const int lm = lane & 15, lg = lane >> 4;
  const int row0 = blockIdx.x * 64;

  f32x4 acc[16];
#pragma unroll
  for (int nf = 0; nf < 16; ++nf) acc[nf] = {0.f, 0.f, 0.f, 0.f};

  for (int k0 = 0; k0 < 256; k0 += 64) {
#pragma unroll
    for (int i = 0; i < 8; ++i) {
      const unsigned short* gp = WbfS +
          (size_t)(w * 64 + i * 8 + (lane >> 3)) * 256 + k0 + (lane & 7) * 8;
      unsigned char* lp = reinterpret_cast<unsigned char*>(Blds) + (w * 8 + i) * 1024;
      __builtin_amdgcn_global_load_lds(
          (const __attribute__((address_space(1))) void*)gp,
          (__attribute__((address_space(3))) void*)lp, 16, 0, 0);
    }
#pragma unroll
    for (int i = 0; i < 4; ++i) {
      int u = i * 256 + t;
      int r = u >> 4, c4 = (u & 15) * 4;
      float4 v = *reinterpret_cast<const float4*>(A + (size_t)(row0 + r) * 256 + k0 + c4);
      ushort4 h;
      h.x = f2bf(v.x); h.y = f2bf(v.y); h.z = f2bf(v.z); h.w = f2bf(v.w);
      *reinterpret_cast<ushort4*>(&Alds[r * 64 + (c4 ^ ((r & 7) << 3))]) = h;
    }
    __syncthreads();

#pragma unroll
    for (int ks = 0; ks < 2; ++ks) {
      const int kk = (ks * 32 + lg * 8) ^ ((lm & 7) << 3);
      const bf16x8 af = *reinterpret_cast<const bf16x8*>(&Alds[(w * 16 + lm) * 64 + kk]);
#pragma unroll
      for (int nf = 0; nf < 16; ++nf) {
        const bf16x8 bfr = *reinterpret_cast<const bf16x8*>(&Blds[(nf * 16 + lm) * 64 + kk]);
        acc[nf] = __builtin_amdgcn_mfma_f32_16x16x32_bf16(af, bfr, acc[nf], 0, 0, 0);
      }
    }
    __syncthreads();
  }

  const int rb = row0 + w * 16 + lg * 4;
#pragma unroll
  for (int nf = 0; nf < 16; ++nf) {
    const int col = nf * 16 + lm;
    const float bv = bias[col];
#pragma unroll
    for (int j = 0; j < 4; ++j)
      C[(size_t)(rb + j) * 256 + col] = __float2bfloat16(acc[nf][j] + bv);
  }
}

// ---------------------------------------------------------------------------
// Fused per-query pipeline, W-read-once-per-block layout.
// Block = 512 threads, 16 queries. launch_bounds (512,2): LDS caps at
// 2 blocks/CU anyway; allows 128 VGPR. Phase 1/3 keep only ONE query's
// float4 live at a time (low reg pressure, LDS broadcast reads).
// ---------------------------------------------------------------------------
#define QPB 16

__global__ __launch_bounds__(512, 2) void fused_query_kernel(
    const float* __restrict__ hidden, const __hip_bfloat16* __restrict__ value,
    const float* __restrict__ refpts,
    const float* __restrict__ W_off, const float* __restrict__ b_off,
    const float* __restrict__ W_attn, const float* __restrict__ b_attn,
    const float* __restrict__ W_out, const float* __restrict__ b_out,
    float* __restrict__ out) {
  __shared__ float s_hid[QPB][256];
  __shared__ float s_off[QPB][256];
  __shared__ float s_lg[QPB][128];
  __shared__ float s_samp[QPB][256];
  __shared__ float s_ref[QPB][4];

  const int nb = gridDim.x;   // 600, divisible by 8
  const int bswz = (blockIdx.x % 8) * (nb / 8) + blockIdx.x / 8;
  const int bq0 = bswz * QPB;
  const int t = threadIdx.x;

  // Phase 0: stage hidden rows + refpts
#pragma unroll
  for (int i = 0; i < QPB * 256 / 512; ++i) {
    int idx = i * 512 + t;
    s_hid[idx >> 8][idx & 255] = hidden[(size_t)bq0 * 256 + idx];
  }
  if (t < QPB * 4) s_ref[t >> 2][t & 3] = refpts[(size_t)bq0 * 4 + t];
  __syncthreads();

  // Phase 1: off (col t&255, q-half t>>8) + attn (col t&127, q-quarter t>>7)
  {
    const int co = t & 255;
    const int ca = t & 127;
    const int qh = t >> 8;             // 0..1  -> queries qh*8 .. qh*8+7
    const int qa = t >> 7;             // 0..3  -> queries qa*4 .. qa*4+3
    float accO[8], accL[4];
#pragma unroll
    for (int c = 0; c < 8; ++c) accO[c] = 0.f;
#pragma unroll
    for (int c = 0; c < 4; ++c) accL[c] = 0.f;
    for (int k0 = 0; k0 < 256; k0 += 4) {
      float wo[4], wa[4];
#pragma unroll
      for (int u = 0; u < 4; ++u) {
        wo[u] = W_off[(size_t)(k0 + u) * 256 + co];
        wa[u] = W_attn[(size_t)(k0 + u) * 128 + ca];
      }
      // one query's float4 live at a time (broadcast LDS reads)
#pragma unroll
      for (int qq = 0; qq < 8; ++qq) {
        const float4 hv = *reinterpret_cast<const float4*>(&s_hid[qh * 8 + qq][k0]);
        accO[qq] += hv.x * wo[0] + hv.y * wo[1] + hv.z * wo[2] + hv.w * wo[3];
      }
#pragma unroll
      for (int j = 0; j < 4; ++j) {
        const float4 hv = *reinterpret_cast<const float4*>(&s_hid[qa * 4 + j][k0]);
        accL[j] += hv.x * wa[0] + hv.y * wa[1] + hv.z * wa[2] + hv.w * wa[3];
      }
    }
    const float bo = b_off[co];
    const float ba = b_attn[ca];
#pragma unroll
    for (int qq = 0; qq < 8; ++qq) s_off[qh * 8 + qq][co] = accO[qq] + bo;
#pragma unroll
    for (int j = 0; j < 4; ++j) s_lg[qa * 4 + j][ca] = accL[j] + ba;
  }
  __syncthreads();

  // Phase 2: softmax (per-head, redundant x4) + bilinear sampling
  {
    const int q = t >> 5;       // 0..15
    const int sub = t & 31;
    const int h = sub >> 2;
    const int c4 = sub & 3;
    const int bq = bq0 + q;
    const int b = bq / QQ;

    float w[16];
    {
      const float* lg = &s_lg[q][h * 16];
      float m = lg[0];
#pragma unroll
      for (int j = 1; j < 16; ++j) m = fmaxf(m, lg[j]);
      float s = 0.f;
#pragma unroll
      for (int j = 0; j < 16; ++j) { w[j] = __expf(lg[j] - m); s += w[j]; }
      float inv = 1.f / s;
#pragma unroll
      for (int j = 0; j < 16; ++j) w[j] *= inv;
    }

    const float rx = s_ref[q][0], ry = s_ref[q][1];
    const float rw = s_ref[q][2], rh = s_ref[q][3];
    const unsigned short* vb =
        (const unsigned short*)value + (size_t)b * SS * DD + h * DHH + c4 * 8;

    float acc[8];
#pragma unroll
    for (int j = 0; j < 8; ++j) acc[j] = 0.f;

    const int dims[4] = {80, 40, 20, 10};
    const int sts[4] = {0, 6400, 8000, 8400};

#pragma unroll
    for (int l = 0; l < LL; ++l) {
      const int dim = dims[l];
      const int st = sts[l];
      const float fdim = (float)dim;
#pragma unroll
      for (int p = 0; p < PP; ++p) {
        const int tapi = l * 4 + p;
        const int oi = (h * 16 + tapi) * 2;
        const float locx = rx + s_off[q][oi] * rw * 0.125f;
        const float locy = ry + s_off[q][oi + 1] * rh * 0.125f;
        const float x = locx * fdim - 0.5f;
        const float y = locy * fdim - 0.5f;
        const float x0f = floorf(x), y0f = floorf(y);
        const float fx = x - x0f, fy = y - y0f;
        const int x0 = (int)x0f, y0 = (int)y0f;
        const float wt = w[tapi];
        const float bw[4] = {(1.f - fx) * (1.f - fy), fx * (1.f - fy),
                             (1.f - fx) * fy, fx * fy};
        const int cx[4] = {x0, x0 + 1, x0, x0 + 1};
        const int cy[4] = {y0, y0, y0 + 1, y0 + 1};
#pragma unroll
        for (int c = 0; c < 4; ++c) {
          const int xi = cx[c], yi = cy[c];
          const bool valid = (xi >= 0) & (xi < dim) & (yi >= 0) & (yi < dim);
          const int xc = min(max(xi, 0), dim - 1);
          const int yc = min(max(yi, 0), dim - 1);
          const uint4 v = *reinterpret_cast<const uint4*>(
              vb + (size_t)(st + yc * dim + xc) * DD);
          const float wv = valid ? bw[c] * wt : 0.f;
          const unsigned u[4] = {v.x, v.y, v.z, v.w};
#pragma unroll
          for (int k = 0; k < 4; ++k) {
            const float lo = __builtin_bit_cast(float, u[k] << 16);
            const float hi = __builtin_bit_cast(float, u[k] & 0xFFFF0000u);
            acc[2 * k] += lo * wv;
            acc[2 * k + 1] += hi * wv;
          }
        }
      }
    }
#pragma unroll
    for (int j = 0; j < 8; ++j) s_samp[q][h * DHH + c4 * 8 + j] = acc[j];
  }
  __syncthreads();

  // Phase 3: out = samp @ W_out + b_out (col t&255, q-half t>>8)
  {
    const int c = t & 255;
    const int qh = t >> 8;
    float accU[8];
#pragma unroll
    for (int qq = 0; qq < 8; ++qq) accU[qq] = 0.f;
    for (int k0 = 0; k0 < 256; k0 += 4) {
      float wu[4];
#pragma unroll
      for (int u = 0; u < 4; ++u) wu[u] = W_out[(size_t)(k0 + u) * 256 + c];
#pragma unroll
      for (int qq = 0; qq < 8; ++qq) {
        const float4 sv = *reinterpret_cast<const float4*>(&s_samp[qh * 8 + qq][k0]);
        accU[qq] += sv.x * wu[0] + sv.y * wu[1] + sv.z * wu[2] + sv.w * wu[3];
      }
    }
    const float bu = b_out[c];
#pragma unroll
    for (int qq = 0; qq < 8; ++qq)
      out[(size_t)(bq0 + qh * 8 + qq) * 256 + c] = accU[qq] + bu;
  }
}

// ---------------------------------------------------------------------------
// Launch
// ---------------------------------------------------------------------------
extern "C" void kernel_launch(void* const* d_in, const int* in_sizes, int n_in,
                              void* d_out, int out_size, void* d_ws, size_t ws_size,
                              hipStream_t stream) {
  const float* hidden = (const float*)d_in[0];
  const float* ehs    = (const float*)d_in[1];
  const float* refpts = (const float*)d_in[2];
  const float* W_val  = (const float*)d_in[3];
  const float* b_val  = (const float*)d_in[4];
  const float* W_off  = (const float*)d_in[5];
  const float* b_off  = (const float*)d_in[6];
  const float* W_attn = (const float*)d_in[7];
  const float* b_attn = (const float*)d_in[8];
  const float* W_out  = (const float*)d_in[9];
  const float* b_out  = (const float*)d_in[10];
  float* out = (float*)d_out;

  // Workspace layout
  char* ws = (char*)d_ws;
  __hip_bfloat16* value = (__hip_bfloat16*)ws;                 // 139,264,000 B
  unsigned short* wbfS = (unsigned short*)(ws + 139264000);    // 131,072 B

  const int M_val = BB * SS;   // 272000
  const int M_q   = BB * QQ;   // 9600

  // 0. W_val -> bf16 [n][k], XOR-swizzled
  wcvt_kernel<<<256, 256, 0, stream>>>(W_val, wbfS);
  // 1. value = ehs @ W_val + b_val  (bf16 MFMA)
  gemm_val_mfma<<<M_val / 64, 256, 0, stream>>>(ehs, wbfS, b_val, value);
  // 2. fused: off/attn projections + softmax + sampling + out projection
  fused_query_kernel<<<M_q / QPB, 512, 0, stream>>>(
      hidden, value, refpts, W_off, b_off, W_attn, b_attn, W_out, b_out, out);
}

// Round 12
// 246.420 us; speedup vs baseline: 4.0964x; 1.1120x over previous
//
#include <hip/hip_runtime.h>
#include <hip/hip_bf16.h>

// Problem constants
#define BB 32
#define QQ 300
#define DD 256
#define HH 8
#define DHH 32
#define LL 4
#define PP 4
#define SS 8500

typedef __attribute__((ext_vector_type(8))) short bf16x8;
typedef __attribute__((ext_vector_type(4))) float f32x4;

__device__ inline unsigned short f2bf(float f) {
  unsigned int u = __builtin_bit_cast(unsigned int, f);
  unsigned int r = (u + 0x7FFFu + ((u >> 16) & 1u)) >> 16;
  return (unsigned short)r;
}

// ---------------------------------------------------------------------------
// Convert W_val (256x256 f32, [k][n]) -> bf16 [n][k] with T2 XOR swizzle
// ---------------------------------------------------------------------------
__global__ __launch_bounds__(256) void wcvt_kernel(const float* __restrict__ W,
                                                   unsigned short* __restrict__ wbfS) {
  int t = blockIdx.x * 256 + threadIdx.x;   // 0..65535
  int k = t >> 8, n = t & 255;              // coalesced read of W[k][*]
  wbfS[n * 256 + (k ^ ((n & 7) << 3))] = f2bf(W[(size_t)k * 256 + n]);
}

// ---------------------------------------------------------------------------
// Value GEMM (unchanged — ~85 us, 4 blocks/CU):
// C[M x 256] = bf16(A[M x 256] f32) @ bf16(W) + bias.
// ---------------------------------------------------------------------------
__global__ __launch_bounds__(256, 4) void gemm_val_mfma(
    const float* __restrict__ A, const unsigned short* __restrict__ WbfS,
    const float* __restrict__ bias, __hip_bfloat16* __restrict__ C) {
  __shared__ __align__(16) unsigned short Alds[64 * 64];  // 8 KB, swizzled
  __shared__ __align__(16) unsigned short Blds[256 * 64]; // 32 KB, swizzled

  const int t = threadIdx.x;
  const int lane = t & 63;
  const int w = t >> 6;
  const int lm = lane & 15, lg = lane >> 4;
  const int row0 = blockIdx.x * 64;

  f32x4 acc[16];
#pragma unroll
  for (int nf = 0; nf < 16; ++nf) acc[nf] = {0.f, 0.f, 0.f, 0.f};

  for (int k0 = 0; k0 < 256; k0 += 64) {
#pragma unroll
    for (int i = 0; i < 8; ++i) {
      const unsigned short* gp = WbfS +
          (size_t)(w * 64 + i * 8 + (lane >> 3)) * 256 + k0 + (lane & 7) * 8;
      unsigned char* lp = reinterpret_cast<unsigned char*>(Blds) + (w * 8 + i) * 1024;
      __builtin_amdgcn_global_load_lds(
          (const __attribute__((address_space(1))) void*)gp,
          (__attribute__((address_space(3))) void*)lp, 16, 0, 0);
    }
#pragma unroll
    for (int i = 0; i < 4; ++i) {
      int u = i * 256 + t;
      int r = u >> 4, c4 = (u & 15) * 4;
      float4 v = *reinterpret_cast<const float4*>(A + (size_t)(row0 + r) * 256 + k0 + c4);
      ushort4 h;
      h.x = f2bf(v.x); h.y = f2bf(v.y); h.z = f2bf(v.z); h.w = f2bf(v.w);
      *reinterpret_cast<ushort4*>(&Alds[r * 64 + (c4 ^ ((r & 7) << 3))]) = h;
    }
    __syncthreads();

#pragma unroll
    for (int ks = 0; ks < 2; ++ks) {
      const int kk = (ks * 32 + lg * 8) ^ ((lm & 7) << 3);
      const bf16x8 af = *reinterpret_cast<const bf16x8*>(&Alds[(w * 16 + lm) * 64 + kk]);
#pragma unroll
      for (int nf = 0; nf < 16; ++nf) {
        const bf16x8 bfr = *reinterpret_cast<const bf16x8*>(&Blds[(nf * 16 + lm) * 64 + kk]);
        acc[nf] = __builtin_amdgcn_mfma_f32_16x16x32_bf16(af, bfr, acc[nf], 0, 0, 0);
      }
    }
    __syncthreads();
  }

  const int rb = row0 + w * 16 + lg * 4;
#pragma unroll
  for (int nf = 0; nf < 16; ++nf) {
    const int col = nf * 16 + lm;
    const float bv = bias[col];
#pragma unroll
    for (int j = 0; j < 4; ++j)
      C[(size_t)(rb + j) * 256 + col] = __float2bfloat16(acc[nf][j] + bv);
  }
}

// ---------------------------------------------------------------------------
// Fused per-query pipeline, W-read-once + 4-column register blocking.
// Block = 512 threads, 16 queries. Phase 1: threads 0-255 do off (4col x 4q),
// threads 256-511 do attn (4col x 2q). Phase 3: all threads, 4col x 2q.
// ds_read_b128 per FMA cut 4x vs R10 (the 55% non-VALU stall was LDS-pipe).
// ---------------------------------------------------------------------------
#define QPB 16

__global__ __launch_bounds__(512, 2) void fused_query_kernel(
    const float* __restrict__ hidden, const __hip_bfloat16* __restrict__ value,
    const float* __restrict__ refpts,
    const float* __restrict__ W_off, const float* __restrict__ b_off,
    const float* __restrict__ W_attn, const float* __restrict__ b_attn,
    const float* __restrict__ W_out, const float* __restrict__ b_out,
    float* __restrict__ out) {
  __shared__ float s_hid[QPB][256];
  __shared__ float s_off[QPB][256];
  __shared__ float s_lg[QPB][128];
  __shared__ float s_samp[QPB][256];
  __shared__ float s_ref[QPB][4];

  const int nb = gridDim.x;   // 600, divisible by 8
  const int bswz = (blockIdx.x % 8) * (nb / 8) + blockIdx.x / 8;
  const int bq0 = bswz * QPB;
  const int t = threadIdx.x;

  // Phase 0: stage hidden rows + refpts
#pragma unroll
  for (int i = 0; i < QPB * 256 / 512; ++i) {
    int idx = i * 512 + t;
    s_hid[idx >> 8][idx & 255] = hidden[(size_t)bq0 * 256 + idx];
  }
  if (t < QPB * 4) s_ref[t >> 2][t & 3] = refpts[(size_t)bq0 * 4 + t];
  __syncthreads();

  // Phase 1: off (thr 0-255: 4 cols x 4 q) | attn (thr 256-511: 4 cols x 2 q)
  if (t < 256) {
    const int cg = t & 63;           // cols cg*4 .. cg*4+3
    const int qg = t >> 6;           // queries qg*4 .. qg*4+3 (wave-uniform)
    float acc[4][4];
#pragma unroll
    for (int j = 0; j < 4; ++j)
#pragma unroll
      for (int c = 0; c < 4; ++c) acc[j][c] = 0.f;
    for (int k0 = 0; k0 < 256; k0 += 4) {
      float4 wv[4];
#pragma unroll
      for (int u = 0; u < 4; ++u)
        wv[u] = *reinterpret_cast<const float4*>(W_off + (size_t)(k0 + u) * 256 + cg * 4);
#pragma unroll
      for (int j = 0; j < 4; ++j) {
        const float4 hv = *reinterpret_cast<const float4*>(&s_hid[qg * 4 + j][k0]);
#pragma unroll
        for (int c = 0; c < 4; ++c) {
          const float wc0 = (&wv[0].x)[c], wc1 = (&wv[1].x)[c];
          const float wc2 = (&wv[2].x)[c], wc3 = (&wv[3].x)[c];
          acc[j][c] += hv.x * wc0 + hv.y * wc1 + hv.z * wc2 + hv.w * wc3;
        }
      }
    }
    const float4 bo = *reinterpret_cast<const float4*>(b_off + cg * 4);
#pragma unroll
    for (int j = 0; j < 4; ++j) {
      float4 r = make_float4(acc[j][0] + bo.x, acc[j][1] + bo.y,
                             acc[j][2] + bo.z, acc[j][3] + bo.w);
      *reinterpret_cast<float4*>(&s_off[qg * 4 + j][cg * 4]) = r;
    }
  } else {
    const int u2 = t - 256;
    const int cg = u2 & 31;          // cols cg*4 .. cg*4+3 (of 128)
    const int qg = u2 >> 5;          // queries qg*2, qg*2+1
    float acc[2][4];
#pragma unroll
    for (int j = 0; j < 2; ++j)
#pragma unroll
      for (int c = 0; c < 4; ++c) acc[j][c] = 0.f;
    for (int k0 = 0; k0 < 256; k0 += 4) {
      float4 wv[4];
#pragma unroll
      for (int u = 0; u < 4; ++u)
        wv[u] = *reinterpret_cast<const float4*>(W_attn + (size_t)(k0 + u) * 128 + cg * 4);
#pragma unroll
      for (int j = 0; j < 2; ++j) {
        const float4 hv = *reinterpret_cast<const float4*>(&s_hid[qg * 2 + j][k0]);
#pragma unroll
        for (int c = 0; c < 4; ++c) {
          const float wc0 = (&wv[0].x)[c], wc1 = (&wv[1].x)[c];
          const float wc2 = (&wv[2].x)[c], wc3 = (&wv[3].x)[c];
          acc[j][c] += hv.x * wc0 + hv.y * wc1 + hv.z * wc2 + hv.w * wc3;
        }
      }
    }
    const float4 ba = *reinterpret_cast<const float4*>(b_attn + cg * 4);
#pragma unroll
    for (int j = 0; j < 2; ++j) {
      float4 r = make_float4(acc[j][0] + ba.x, acc[j][1] + ba.y,
                             acc[j][2] + ba.z, acc[j][3] + ba.w);
      *reinterpret_cast<float4*>(&s_lg[qg * 2 + j][cg * 4]) = r;
    }
  }
  __syncthreads();

  // Phase 2: softmax (per-head, redundant x4) + bilinear sampling
  {
    const int q = t >> 5;       // 0..15
    const int sub = t & 31;
    const int h = sub >> 2;
    const int c4 = sub & 3;
    const int bq = bq0 + q;
    const int b = bq / QQ;

    float w[16];
    {
      const float* lg = &s_lg[q][h * 16];
      float m = lg[0];
#pragma unroll
      for (int j = 1; j < 16; ++j) m = fmaxf(m, lg[j]);
      float s = 0.f;
#pragma unroll
      for (int j = 0; j < 16; ++j) { w[j] = __expf(lg[j] - m); s += w[j]; }
      float inv = 1.f / s;
#pragma unroll
      for (int j = 0; j < 16; ++j) w[j] *= inv;
    }

    const float rx = s_ref[q][0], ry = s_ref[q][1];
    const float rw = s_ref[q][2], rh = s_ref[q][3];
    const unsigned short* vb =
        (const unsigned short*)value + (size_t)b * SS * DD + h * DHH + c4 * 8;

    float acc[8];
#pragma unroll
    for (int j = 0; j < 8; ++j) acc[j] = 0.f;

    const int dims[4] = {80, 40, 20, 10};
    const int sts[4] = {0, 6400, 8000, 8400};

#pragma unroll
    for (int l = 0; l < LL; ++l) {
      const int dim = dims[l];
      const int st = sts[l];
      const float fdim = (float)dim;
#pragma unroll
      for (int p = 0; p < PP; ++p) {
        const int tapi = l * 4 + p;
        const int oi = (h * 16 + tapi) * 2;
        const float locx = rx + s_off[q][oi] * rw * 0.125f;
        const float locy = ry + s_off[q][oi + 1] * rh * 0.125f;
        const float x = locx * fdim - 0.5f;
        const float y = locy * fdim - 0.5f;
        const float x0f = floorf(x), y0f = floorf(y);
        const float fx = x - x0f, fy = y - y0f;
        const int x0 = (int)x0f, y0 = (int)y0f;
        const float wt = w[tapi];
        const float bw[4] = {(1.f - fx) * (1.f - fy), fx * (1.f - fy),
                             (1.f - fx) * fy, fx * fy};
        const int cx[4] = {x0, x0 + 1, x0, x0 + 1};
        const int cy[4] = {y0, y0, y0 + 1, y0 + 1};
#pragma unroll
        for (int c = 0; c < 4; ++c) {
          const int xi = cx[c], yi = cy[c];
          const bool valid = (xi >= 0) & (xi < dim) & (yi >= 0) & (yi < dim);
          const int xc = min(max(xi, 0), dim - 1);
          const int yc = min(max(yi, 0), dim - 1);
          const uint4 v = *reinterpret_cast<const uint4*>(
              vb + (size_t)(st + yc * dim + xc) * DD);
          const float wv = valid ? bw[c] * wt : 0.f;
          const unsigned u[4] = {v.x, v.y, v.z, v.w};
#pragma unroll
          for (int k = 0; k < 4; ++k) {
            const float lo = __builtin_bit_cast(float, u[k] << 16);
            const float hi = __builtin_bit_cast(float, u[k] & 0xFFFF0000u);
            acc[2 * k] += lo * wv;
            acc[2 * k + 1] += hi * wv;
          }
        }
      }
    }
#pragma unroll
    for (int j = 0; j < 8; ++j) s_samp[q][h * DHH + c4 * 8 + j] = acc[j];
  }
  __syncthreads();

  // Phase 3: out = samp @ W_out + b_out (all threads: 4 cols x 2 q)
  {
    const int cg = t & 63;           // cols cg*4 .. cg*4+3
    const int qg = t >> 6;           // queries qg*2, qg*2+1
    float acc[2][4];
#pragma unroll
    for (int j = 0; j < 2; ++j)
#pragma unroll
      for (int c = 0; c < 4; ++c) acc[j][c] = 0.f;
    for (int k0 = 0; k0 < 256; k0 += 4) {
      float4 wv[4];
#pragma unroll
      for (int u = 0; u < 4; ++u)
        wv[u] = *reinterpret_cast<const float4*>(W_out + (size_t)(k0 + u) * 256 + cg * 4);
#pragma unroll
      for (int j = 0; j < 2; ++j) {
        const float4 sv = *reinterpret_cast<const float4*>(&s_samp[qg * 2 + j][k0]);
#pragma unroll
        for (int c = 0; c < 4; ++c) {
          const float wc0 = (&wv[0].x)[c], wc1 = (&wv[1].x)[c];
          const float wc2 = (&wv[2].x)[c], wc3 = (&wv[3].x)[c];
          acc[j][c] += sv.x * wc0 + sv.y * wc1 + sv.z * wc2 + sv.w * wc3;
        }
      }
    }
    const float4 bu = *reinterpret_cast<const float4*>(b_out + cg * 4);
#pragma unroll
    for (int j = 0; j < 2; ++j) {
      float4 r = make_float4(acc[j][0] + bu.x, acc[j][1] + bu.y,
                             acc[j][2] + bu.z, acc[j][3] + bu.w);
      *reinterpret_cast<float4*>(out + (size_t)(bq0 + qg * 2 + j) * 256 + cg * 4) = r;
    }
  }
}

// ---------------------------------------------------------------------------
// Launch
// ---------------------------------------------------------------------------
extern "C" void kernel_launch(void* const* d_in, const int* in_sizes, int n_in,
                              void* d_out, int out_size, void* d_ws, size_t ws_size,
                              hipStream_t stream) {
  const float* hidden = (const float*)d_in[0];
  const float* ehs    = (const float*)d_in[1];
  const float* refpts = (const float*)d_in[2];
  const float* W_val  = (const float*)d_in[3];
  const float* b_val  = (const float*)d_in[4];
  const float* W_off  = (const float*)d_in[5];
  const float* b_off  = (const float*)d_in[6];
  const float* W_attn = (const float*)d_in[7];
  const float* b_attn = (const float*)d_in[8];
  const float* W_out  = (const float*)d_in[9];
  const float* b_out  = (const float*)d_in[10];
  float* out = (float*)d_out;

  // Workspace layout
  char* ws = (char*)d_ws;
  __hip_bfloat16* value = (__hip_bfloat16*)ws;                 // 139,264,000 B
  unsigned short* wbfS = (unsigned short*)(ws + 139264000);    // 131,072 B

  const int M_val = BB * SS;   // 272000
  const int M_q   = BB * QQ;   // 9600

  // 0. W_val -> bf16 [n][k], XOR-swizzled
  wcvt_kernel<<<256, 256, 0, stream>>>(W_val, wbfS);
  // 1. value = ehs @ W_val + b_val  (bf16 MFMA)
  gemm_val_mfma<<<M_val / 64, 256, 0, stream>>>(ehs, wbfS, b_val, value);
  // 2. fused: off/attn projections + softmax + sampling + out projection
  fused_query_kernel<<<M_q / QPB, 512, 0, stream>>>(
      hidden, value, refpts, W_off, b_off, W_attn, b_attn, W_out, b_out, out);
}